// Round 2
// baseline (589.278 us; speedup 1.0000x reference)
//
#include <hip/hip_runtime.h>
#include <hip/hip_bf16.h>
#include <math.h>

#define T_SEQ 2048
#define NB 2
#define C_DIM 768
#define NH 12

typedef unsigned short ushort_t;
typedef __attribute__((ext_vector_type(8))) short short8;
typedef __attribute__((ext_vector_type(8))) unsigned short ushort8;
typedef __attribute__((ext_vector_type(4))) float floatx4;

__device__ inline float bf2f(ushort_t u) {
    unsigned int x = ((unsigned int)u) << 16;
    return __uint_as_float(x);
}
__device__ inline ushort_t f2bf(float f) {
    unsigned int u = __float_as_uint(f);
    unsigned int r = (u + 0x7fffu + ((u >> 16) & 1u)) >> 16;
    return (ushort_t)r;
}

// ---------------- LayerNorm: fp32 in -> bf16 out, one block per row of 768 ----------------
__global__ __launch_bounds__(256) void ln_kernel(const float* __restrict__ x,
                                                 const float* __restrict__ g,
                                                 const float* __restrict__ b,
                                                 ushort_t* __restrict__ out) {
    int row = blockIdx.x;
    int tid = threadIdx.x;
    int lane = tid & 63, wave = tid >> 6;
    const float* xr = x + (size_t)row * C_DIM;
    float v0 = xr[tid];
    float v1 = xr[tid + 256];
    float v2 = xr[tid + 512];
    float s = v0 + v1 + v2;
#pragma unroll
    for (int m = 32; m > 0; m >>= 1) s += __shfl_xor(s, m, 64);
    __shared__ float red[8];
    if (lane == 0) red[wave] = s;
    __syncthreads();
    float mean = (red[0] + red[1] + red[2] + red[3]) * (1.0f / C_DIM);
    float d0 = v0 - mean, d1 = v1 - mean, d2 = v2 - mean;
    float q = d0 * d0 + d1 * d1 + d2 * d2;
#pragma unroll
    for (int m = 32; m > 0; m >>= 1) q += __shfl_xor(q, m, 64);
    if (lane == 0) red[wave + 4] = q;
    __syncthreads();
    float var = (red[4] + red[5] + red[6] + red[7]) * (1.0f / C_DIM);
    float rstd = rsqrtf(var + 1e-5f);
    ushort_t* orow = out + (size_t)row * C_DIM;
    orow[tid]       = f2bf(d0 * rstd * g[tid]       + b[tid]);
    orow[tid + 256] = f2bf(d1 * rstd * g[tid + 256] + b[tid + 256]);
    orow[tid + 512] = f2bf(d2 * rstd * g[tid + 512] + b[tid + 512]);
}

// ---------------- GEMM: C[M,N] = A[M,K](bf16) @ B[K,N](fp32 weights) (+epilogue) ----------------
// EPI: 0 = none, 1 = +res, 2 = +bias then erf-GELU, 3 = +bias +res.  OUT_F32: output dtype.
template <int EPI, int OUT_F32>
__global__ __launch_bounds__(256) void gemm_kernel(const ushort_t* __restrict__ A,
                                                   const float* __restrict__ B,
                                                   const float* __restrict__ bias,
                                                   const float* __restrict__ res,
                                                   void* __restrict__ Cout,
                                                   int M, int N, int K) {
    __shared__ ushort_t As[64 * 32];  // [m][k]
    __shared__ ushort_t Bs[64 * 32];  // transposed: [n][k]
    int tid = threadIdx.x;
    int lane = tid & 63, wave = tid >> 6;
    int lane15 = lane & 15, quad = lane >> 4;
    int row0 = blockIdx.x * 64;
    int col0 = blockIdx.y * 64;
    floatx4 acc[4];
    floatx4 zero = {0.f, 0.f, 0.f, 0.f};
#pragma unroll
    for (int nt = 0; nt < 4; nt++) acc[nt] = zero;

    int a_row = tid >> 2, a_col = (tid & 3) << 3;   // 64 rows x 32 cols
    int b_k = tid >> 3, b_n = (tid & 7) << 3;       // 32 rows x 64 cols
    const ushort_t* ap = A + (size_t)(row0 + a_row) * K + a_col;
    const float* bp = B + (size_t)b_k * N + col0 + b_n;

    for (int k0 = 0; k0 < K; k0 += 32) {
        ushort8 av = *(const ushort8*)(ap + k0);
        const float* bsrc = bp + (size_t)k0 * N;
        floatx4 b0 = *(const floatx4*)(bsrc);
        floatx4 b1 = *(const floatx4*)(bsrc + 4);
        *(ushort8*)&As[a_row * 32 + a_col] = av;
#pragma unroll
        for (int j = 0; j < 4; j++) Bs[(b_n + j) * 32 + b_k]     = f2bf(b0[j]);
#pragma unroll
        for (int j = 0; j < 4; j++) Bs[(b_n + 4 + j) * 32 + b_k] = f2bf(b1[j]);
        __syncthreads();
        short8 af = *(const short8*)&As[(wave * 16 + lane15) * 32 + (quad << 3)];
#pragma unroll
        for (int nt = 0; nt < 4; nt++) {
            short8 bfm = *(const short8*)&Bs[(nt * 16 + lane15) * 32 + (quad << 3)];
            acc[nt] = __builtin_amdgcn_mfma_f32_16x16x32_bf16(af, bfm, acc[nt], 0, 0, 0);
        }
        __syncthreads();
    }

    int r_base = row0 + wave * 16 + (quad << 2);
    int c_base = col0 + lane15;
    ushort_t* out_bf = (ushort_t*)Cout;
    float* out_f = (float*)Cout;
#pragma unroll
    for (int nt = 0; nt < 4; nt++) {
        int cc = c_base + nt * 16;
        float bvv = 0.f;
        if (EPI == 2 || EPI == 3) bvv = bias[cc];
#pragma unroll
        for (int r = 0; r < 4; r++) {
            int rr = r_base + r;
            float v = acc[nt][r] + bvv;
            if (EPI == 2) v = 0.5f * v * (1.f + erff(v * 0.70710678118f));
            if (EPI == 1 || EPI == 3) v += res[(size_t)rr * N + cc];
            if (OUT_F32) out_f[(size_t)rr * N + cc] = v;
            else out_bf[(size_t)rr * N + cc] = f2bf(v);
        }
    }
}

// ---------------- Flash attention: block = (64 queries) x (b,h), qkv bf16 ----------------
__global__ __launch_bounds__(256) void attn_kernel(const ushort_t* __restrict__ qkv,
                                                   ushort_t* __restrict__ y) {
    __shared__ ushort_t Vt[64 * 32];     // [d][key]  (transposed V tile)
    __shared__ ushort_t Ps[4][16 * 32];  // per-wave P tile [qrow][key]
    int tid = threadIdx.x, lane = tid & 63, wave = tid >> 6;
    int lane15 = lane & 15, quad = lane >> 4;
    int qb = blockIdx.x * 64;
    int h = blockIdx.y;
    int b = blockIdx.z;
    const ushort_t* base = qkv + (size_t)b * T_SEQ * 2304;

    // Q fragments (scaled by 1/8 exactly)
    int qrow = qb + wave * 16 + lane15;
    short8 qf[2];
#pragma unroll
    for (int c = 0; c < 2; c++) {
        const ushort_t* qp = base + (size_t)qrow * 2304 + h * 64 + c * 32 + quad * 8;
        ushort8 qv = *(const ushort8*)qp;
        short8 qs;
#pragma unroll
        for (int j = 0; j < 8; j++) qs[j] = (short)f2bf(bf2f(qv[j]) * 0.125f);
        qf[c] = qs;
    }

    floatx4 o[4];
    floatx4 zero = {0.f, 0.f, 0.f, 0.f};
#pragma unroll
    for (int nt = 0; nt < 4; nt++) o[nt] = zero;
    float m_i[4], l_i[4];
#pragma unroll
    for (int r = 0; r < 4; r++) { m_i[r] = -1e30f; l_i[r] = 0.f; }

    int kend = qb + 64;
    int qmax_wave = qb + wave * 16 + 15;
    int vkey = tid >> 3, vd = (tid & 7) << 3;

    for (int kb = 0; kb < kend; kb += 32) {
        // stage V transposed
        {
            const ushort_t* vp = base + (size_t)(kb + vkey) * 2304 + 1536 + h * 64 + vd;
            ushort8 vv = *(const ushort8*)vp;
#pragma unroll
            for (int j = 0; j < 8; j++) Vt[(vd + j) * 32 + vkey] = vv[j];
        }
        __syncthreads();
        if (kb <= qmax_wave) {
            float sv[2][4];
#pragma unroll
            for (int sb = 0; sb < 2; sb++) {
                floatx4 s = zero;
                int key = kb + sb * 16 + lane15;
#pragma unroll
                for (int c = 0; c < 2; c++) {
                    const ushort_t* kp = base + (size_t)key * 2304 + 768 + h * 64 + c * 32 + quad * 8;
                    short8 kf = *(const short8*)kp;
                    s = __builtin_amdgcn_mfma_f32_16x16x32_bf16(qf[c], kf, s, 0, 0, 0);
                }
#pragma unroll
                for (int r = 0; r < 4; r++) {
                    int q_r = qb + wave * 16 + quad * 4 + r;
                    sv[sb][r] = (key > q_r) ? -INFINITY : s[r];
                }
            }
            // online softmax (rows live in 16-lane groups)
#pragma unroll
            for (int r = 0; r < 4; r++) {
                float mx = fmaxf(sv[0][r], sv[1][r]);
#pragma unroll
                for (int msk = 1; msk < 16; msk <<= 1) mx = fmaxf(mx, __shfl_xor(mx, msk, 64));
                float m_new = fmaxf(m_i[r], mx);
                float alpha = __expf(m_i[r] - m_new);
                float p0 = __expf(sv[0][r] - m_new);
                float p1 = __expf(sv[1][r] - m_new);
                float rs = p0 + p1;
#pragma unroll
                for (int msk = 1; msk < 16; msk <<= 1) rs += __shfl_xor(rs, msk, 64);
                l_i[r] = l_i[r] * alpha + rs;
                m_i[r] = m_new;
#pragma unroll
                for (int nt = 0; nt < 4; nt++) o[nt][r] *= alpha;
                Ps[wave][(quad * 4 + r) * 32 + lane15] = f2bf(p0);
                Ps[wave][(quad * 4 + r) * 32 + 16 + lane15] = f2bf(p1);
            }
            // P (C-layout) -> A-layout via per-wave LDS round trip
            short8 pf = *(const short8*)&Ps[wave][lane15 * 32 + quad * 8];
#pragma unroll
            for (int nt = 0; nt < 4; nt++) {
                short8 vf = *(const short8*)&Vt[(nt * 16 + lane15) * 32 + quad * 8];
                o[nt] = __builtin_amdgcn_mfma_f32_16x16x32_bf16(pf, vf, o[nt], 0, 0, 0);
            }
        }
        __syncthreads();
    }

    ushort_t* yb = y + (size_t)b * T_SEQ * 768;
#pragma unroll
    for (int r = 0; r < 4; r++) {
        float rcp = 1.f / l_i[r];
        int q_r = qb + wave * 16 + quad * 4 + r;
#pragma unroll
        for (int nt = 0; nt < 4; nt++) {
            yb[(size_t)q_r * 768 + h * 64 + nt * 16 + lane15] = f2bf(o[nt][r] * rcp);
        }
    }
}

extern "C" void kernel_launch(void* const* d_in, const int* in_sizes, int n_in,
                              void* d_out, int out_size, void* d_ws, size_t ws_size,
                              hipStream_t stream) {
    (void)in_sizes; (void)n_in; (void)out_size; (void)ws_size;
    const float* x      = (const float*)d_in[0];
    const float* ln1_g  = (const float*)d_in[1];
    const float* ln1_b  = (const float*)d_in[2];
    const float* w_qkv  = (const float*)d_in[3];
    const float* w_o    = (const float*)d_in[4];
    const float* ln2_g  = (const float*)d_in[5];
    const float* ln2_b  = (const float*)d_in[6];
    const float* w_fc   = (const float*)d_in[7];
    const float* b_fc   = (const float*)d_in[8];
    const float* w_proj = (const float*)d_in[9];
    const float* b_proj = (const float*)d_in[10];

    char* ws = (char*)d_ws;
    // Layout (bytes):
    //   [0,          18874368)  qkv   bf16  4096x2304
    //   [18874368,   25165824)  ybuf  bf16  4096x768
    //   [0,          25165824)  hff   bf16  4096x3072  (aliases qkv+ybuf, both dead)
    //   [25165824,   37748736)  x2    fp32  4096x768
    //   [37748736,   44040192)  xn    bf16  4096x768
    ushort_t* qkv  = (ushort_t*)(ws);
    ushort_t* ybuf = (ushort_t*)(ws + 18874368);
    ushort_t* hff  = (ushort_t*)(ws);
    float*    x2   = (float*)(ws + 25165824);
    ushort_t* xn   = (ushort_t*)(ws + 37748736);

    const int M = NB * T_SEQ;  // 4096

    ln_kernel<<<dim3(M), 256, 0, stream>>>(x, ln1_g, ln1_b, xn);
    gemm_kernel<0, 0><<<dim3(M / 64, 2304 / 64), 256, 0, stream>>>(xn, w_qkv, nullptr, nullptr, qkv, M, 2304, 768);
    attn_kernel<<<dim3(T_SEQ / 64, NH, NB), 256, 0, stream>>>(qkv, ybuf);
    gemm_kernel<1, 1><<<dim3(M / 64, 768 / 64), 256, 0, stream>>>(ybuf, w_o, nullptr, x, x2, M, 768, 768);
    ln_kernel<<<dim3(M), 256, 0, stream>>>((const float*)x2, ln2_g, ln2_b, xn);
    gemm_kernel<2, 0><<<dim3(M / 64, 3072 / 64), 256, 0, stream>>>(xn, w_fc, b_fc, nullptr, hff, M, 3072, 768);
    gemm_kernel<3, 1><<<dim3(M / 64, 768 / 64), 256, 0, stream>>>(hff, w_proj, b_proj, x2, d_out, M, 768, 3072);
}

// Round 3
// 449.087 us; speedup vs baseline: 1.3122x; 1.3122x over previous
//
#include <hip/hip_runtime.h>
#include <hip/hip_bf16.h>
#include <math.h>

#define T_SEQ 2048
#define NB 2
#define C_DIM 768
#define NH 12

typedef unsigned short ushort_t;
typedef __attribute__((ext_vector_type(8))) short short8;
typedef __attribute__((ext_vector_type(8))) unsigned short ushort8;
typedef __attribute__((ext_vector_type(4))) float floatx4;

__device__ inline float bf2f(ushort_t u) {
    unsigned int x = ((unsigned int)u) << 16;
    return __uint_as_float(x);
}
__device__ inline ushort_t f2bf(float f) {
    unsigned int u = __float_as_uint(f);
    unsigned int r = (u + 0x7fffu + ((u >> 16) & 1u)) >> 16;
    return (ushort_t)r;
}

#if defined(__has_builtin)
#if __has_builtin(__builtin_amdgcn_global_load_lds)
#define HAVE_GLL 1
#endif
#endif

__device__ inline void gload_lds16(const ushort_t* g, ushort_t* l) {
#ifdef HAVE_GLL
    __builtin_amdgcn_global_load_lds(
        (const __attribute__((address_space(1))) void*)g,
        (__attribute__((address_space(3))) void*)l, 16, 0, 0);
#else
    // fallback: synchronous, same layout (lane writes its own 16B slot)
    int lane = threadIdx.x & 63;
    *(ushort8*)(l + lane * 8) = *(const ushort8*)g;
#endif
}

// ---------------- LayerNorm: fp32 in -> bf16 out, one block per row of 768 ----------------
__global__ __launch_bounds__(256) void ln_kernel(const float* __restrict__ x,
                                                 const float* __restrict__ g,
                                                 const float* __restrict__ b,
                                                 ushort_t* __restrict__ out) {
    int row = blockIdx.x;
    int tid = threadIdx.x;
    int lane = tid & 63, wave = tid >> 6;
    const float* xr = x + (size_t)row * C_DIM;
    float v0 = xr[tid];
    float v1 = xr[tid + 256];
    float v2 = xr[tid + 512];
    float s = v0 + v1 + v2;
#pragma unroll
    for (int m = 32; m > 0; m >>= 1) s += __shfl_xor(s, m, 64);
    __shared__ float red[8];
    if (lane == 0) red[wave] = s;
    __syncthreads();
    float mean = (red[0] + red[1] + red[2] + red[3]) * (1.0f / C_DIM);
    float d0 = v0 - mean, d1 = v1 - mean, d2 = v2 - mean;
    float q = d0 * d0 + d1 * d1 + d2 * d2;
#pragma unroll
    for (int m = 32; m > 0; m >>= 1) q += __shfl_xor(q, m, 64);
    if (lane == 0) red[wave + 4] = q;
    __syncthreads();
    float var = (red[4] + red[5] + red[6] + red[7]) * (1.0f / C_DIM);
    float rstd = rsqrtf(var + 1e-5f);
    ushort_t* orow = out + (size_t)row * C_DIM;
    orow[tid]       = f2bf(d0 * rstd * g[tid]       + b[tid]);
    orow[tid + 256] = f2bf(d1 * rstd * g[tid + 256] + b[tid + 256]);
    orow[tid + 512] = f2bf(d2 * rstd * g[tid + 512] + b[tid + 512]);
}

// ------------- Weight convert+transpose: W[K][N] fp32 -> WT[N][K] bf16, 64x64 tiles -------------
__global__ __launch_bounds__(256) void wconv_kernel(const float* __restrict__ W,
                                                    ushort_t* __restrict__ WT,
                                                    int K, int N) {
    __shared__ ushort_t Tls[64 * 72];
    int tid = threadIdx.x;
    int k0 = blockIdx.x * 64, n0 = blockIdx.y * 64;
    int nl = (tid & 15) * 4;
    int kl = tid >> 4;
#pragma unroll
    for (int rr = 0; rr < 4; rr++) {
        int k = kl + rr * 16;
        floatx4 v = *(const floatx4*)&W[(size_t)(k0 + k) * N + n0 + nl];
#pragma unroll
        for (int j = 0; j < 4; j++) Tls[(nl + j) * 72 + k] = f2bf(v[j]);
    }
    __syncthreads();
    int no = tid >> 3;
    int ko = (tid & 7) * 8;
#pragma unroll
    for (int rr = 0; rr < 2; rr++) {
        int n = no + rr * 32;
        ushort8 t = *(const ushort8*)&Tls[n * 72 + ko];
        *(ushort8*)&WT[(size_t)(n0 + n) * K + k0 + ko] = t;
    }
}

// ------------- V transpose: qkv[b][t][1536+h*64+d] -> vt[b][h][d][t], 64x64 tiles -------------
__global__ __launch_bounds__(256) void vtrans_kernel(const ushort_t* __restrict__ qkv,
                                                     ushort_t* __restrict__ vt) {
    __shared__ ushort_t Tls[64 * 72];
    int tid = threadIdx.x;
    int t0 = blockIdx.x * 64;
    int h = blockIdx.y, b = blockIdx.z;
    const ushort_t* src = qkv + (size_t)b * T_SEQ * 2304 + 1536 + h * 64;
    int tl = tid >> 3, dl = (tid & 7) * 8;
#pragma unroll
    for (int rr = 0; rr < 2; rr++) {
        int t = tl + rr * 32;
        ushort8 v = *(const ushort8*)&src[(size_t)(t0 + t) * 2304 + dl];
#pragma unroll
        for (int j = 0; j < 8; j++) Tls[(dl + j) * 72 + t] = v[j];
    }
    __syncthreads();
    int dd = tid >> 3, tt = (tid & 7) * 8;
#pragma unroll
    for (int rr = 0; rr < 2; rr++) {
        int d = dd + rr * 32;
        ushort8 v = *(const ushort8*)&Tls[d * 72 + tt];
        *(ushort8*)&vt[((size_t)(b * NH + h) * 64 + d) * 2048 + t0 + tt] = v;
    }
}

// ---------------- GEMM (m97-style): C[M,N] = A[M,K](bf16) @ BT[N,K](bf16) ----------------
// EPI: 0 = none, 1 = +res, 2 = +bias then erf-GELU, 3 = +bias +res.  OUT_F32: output dtype.
template <int EPI, int OUT_F32>
__global__ __launch_bounds__(256) void gemm_bt_kernel(const ushort_t* __restrict__ A,
                                                      const ushort_t* __restrict__ BT,
                                                      const float* __restrict__ bias,
                                                      const float* __restrict__ res,
                                                      void* __restrict__ Cout,
                                                      int M, int N, int K) {
    __shared__ ushort_t As[128 * 32];
    __shared__ ushort_t Bs[128 * 32];
    int tid = threadIdx.x;
    int lane = tid & 63, wave = tid >> 6;
    int lane15 = lane & 15, quad = lane >> 4;
    int wr = wave >> 1, wc = wave & 1;
    int row0 = blockIdx.x * 128, col0 = blockIdx.y * 128;

    int sub_row = lane >> 2;        // 0..15
    int sub_k = (lane & 3) * 8;     // 0,8,16,24
    const ushort_t* agp0 = A + (size_t)(row0 + wave * 32 + sub_row) * K + sub_k;
    const ushort_t* agp1 = agp0 + (size_t)16 * K;
    const ushort_t* bgp0 = BT + (size_t)(col0 + wave * 32 + sub_row) * K + sub_k;
    const ushort_t* bgp1 = bgp0 + (size_t)16 * K;
    ushort_t* lA0 = &As[wave * 1024];
    ushort_t* lA1 = lA0 + 512;
    ushort_t* lB0 = &Bs[wave * 1024];
    ushort_t* lB1 = lB0 + 512;

    floatx4 acc[4][4];
    floatx4 zero = {0.f, 0.f, 0.f, 0.f};
#pragma unroll
    for (int mt = 0; mt < 4; mt++)
#pragma unroll
        for (int nt = 0; nt < 4; nt++) acc[mt][nt] = zero;

    for (int k0 = 0; k0 < K; k0 += 32) {
        gload_lds16(agp0 + k0, lA0);
        gload_lds16(agp1 + k0, lA1);
        gload_lds16(bgp0 + k0, lB0);
        gload_lds16(bgp1 + k0, lB1);
        __syncthreads();
        short8 af[4], bfm[4];
#pragma unroll
        for (int mt = 0; mt < 4; mt++)
            af[mt] = *(const short8*)&As[(wr * 64 + mt * 16 + lane15) * 32 + quad * 8];
#pragma unroll
        for (int nt = 0; nt < 4; nt++)
            bfm[nt] = *(const short8*)&Bs[(wc * 64 + nt * 16 + lane15) * 32 + quad * 8];
#pragma unroll
        for (int mt = 0; mt < 4; mt++)
#pragma unroll
            for (int nt = 0; nt < 4; nt++)
                acc[mt][nt] = __builtin_amdgcn_mfma_f32_16x16x32_bf16(af[mt], bfm[nt], acc[mt][nt], 0, 0, 0);
        __syncthreads();
    }

    ushort_t* out_bf = (ushort_t*)Cout;
    float* out_f = (float*)Cout;
#pragma unroll
    for (int mt = 0; mt < 4; mt++) {
        int r_base = row0 + wr * 64 + mt * 16 + quad * 4;
#pragma unroll
        for (int nt = 0; nt < 4; nt++) {
            int cc = col0 + wc * 64 + nt * 16 + lane15;
            float bvv = 0.f;
            if (EPI == 2 || EPI == 3) bvv = bias[cc];
#pragma unroll
            for (int r = 0; r < 4; r++) {
                int rr = r_base + r;
                float v = acc[mt][nt][r] + bvv;
                if (EPI == 2) v = 0.5f * v * (1.f + erff(v * 0.70710678118f));
                if (EPI == 1 || EPI == 3) v += res[(size_t)rr * N + cc];
                if (OUT_F32) out_f[(size_t)rr * N + cc] = v;
                else out_bf[(size_t)rr * N + cc] = f2bf(v);
            }
        }
    }
}

// ---------------- Flash attention: sync-free, one wave per 16 queries ----------------
__global__ __launch_bounds__(256) void attn_kernel(const ushort_t* __restrict__ qkv,
                                                   const ushort_t* __restrict__ vt,
                                                   ushort_t* __restrict__ y) {
    __shared__ ushort_t Ps[4][16 * 40];  // per-wave P tile, stride 40 (16B-aligned rows)
    int tid = threadIdx.x, lane = tid & 63, wave = tid >> 6;
    int lane15 = lane & 15, quad = lane >> 4;
    int qrow0 = blockIdx.x * 64 + wave * 16;
    int h = blockIdx.y;
    int b = blockIdx.z;
    const ushort_t* base = qkv + (size_t)b * T_SEQ * 2304;
    const ushort_t* vbase = vt + (size_t)(b * NH + h) * 64 * 2048;

    // Q fragments (scaled by 1/8, exact in bf16)
    int qr = qrow0 + lane15;
    short8 qf[2];
#pragma unroll
    for (int c = 0; c < 2; c++) {
        const ushort_t* qp = base + (size_t)qr * 2304 + h * 64 + c * 32 + quad * 8;
        ushort8 qv = *(const ushort8*)qp;
        short8 qs;
#pragma unroll
        for (int j = 0; j < 8; j++) qs[j] = (short)f2bf(bf2f(qv[j]) * 0.125f);
        qf[c] = qs;
    }

    floatx4 o[4];
    floatx4 zero = {0.f, 0.f, 0.f, 0.f};
#pragma unroll
    for (int nt = 0; nt < 4; nt++) o[nt] = zero;
    float m_i[4], l_i[4];
#pragma unroll
    for (int r = 0; r < 4; r++) { m_i[r] = -1e30f; l_i[r] = 0.f; }

    int kend = qrow0 + 16;

    // preload K fragments for kb = 0
    short8 kf[2][2];
#pragma unroll
    for (int sb = 0; sb < 2; sb++) {
        int key = sb * 16 + lane15;
#pragma unroll
        for (int c = 0; c < 2; c++)
            kf[sb][c] = *(const short8*)(base + (size_t)key * 2304 + 768 + h * 64 + c * 32 + quad * 8);
    }

    for (int kb = 0; kb < kend; kb += 32) {
        // V fragments (direct from transposed V, contiguous)
        short8 vf[4];
#pragma unroll
        for (int nt = 0; nt < 4; nt++)
            vf[nt] = *(const short8*)&vbase[(size_t)(nt * 16 + lane15) * 2048 + kb + quad * 8];

        floatx4 s0 = zero, s1 = zero;
        s0 = __builtin_amdgcn_mfma_f32_16x16x32_bf16(qf[0], kf[0][0], s0, 0, 0, 0);
        s0 = __builtin_amdgcn_mfma_f32_16x16x32_bf16(qf[1], kf[0][1], s0, 0, 0, 0);
        s1 = __builtin_amdgcn_mfma_f32_16x16x32_bf16(qf[0], kf[1][0], s1, 0, 0, 0);
        s1 = __builtin_amdgcn_mfma_f32_16x16x32_bf16(qf[1], kf[1][1], s1, 0, 0, 0);

        // prefetch next K tile
        int kb2 = kb + 32;
        if (kb2 < kend) {
#pragma unroll
            for (int sb = 0; sb < 2; sb++) {
                int key = kb2 + sb * 16 + lane15;
#pragma unroll
                for (int c = 0; c < 2; c++)
                    kf[sb][c] = *(const short8*)(base + (size_t)key * 2304 + 768 + h * 64 + c * 32 + quad * 8);
            }
        }

        float sv[2][4];
#pragma unroll
        for (int r = 0; r < 4; r++) { sv[0][r] = s0[r]; sv[1][r] = s1[r]; }
        if (kb + 32 > qrow0) {  // wave-uniform: only the last iteration masks
#pragma unroll
            for (int sb = 0; sb < 2; sb++) {
                int key = kb + sb * 16 + lane15;
#pragma unroll
                for (int r = 0; r < 4; r++) {
                    int q_r = qrow0 + quad * 4 + r;
                    if (key > q_r) sv[sb][r] = -INFINITY;
                }
            }
        }

        // online softmax (rows spread across 16-lane groups)
#pragma unroll
        for (int r = 0; r < 4; r++) {
            float mx = fmaxf(sv[0][r], sv[1][r]);
#pragma unroll
            for (int msk = 1; msk < 16; msk <<= 1) mx = fmaxf(mx, __shfl_xor(mx, msk, 64));
            float m_new = fmaxf(m_i[r], mx);
            float alpha = __expf(m_i[r] - m_new);
            float p0 = __expf(sv[0][r] - m_new);
            float p1 = __expf(sv[1][r] - m_new);
            float rs = p0 + p1;
#pragma unroll
            for (int msk = 1; msk < 16; msk <<= 1) rs += __shfl_xor(rs, msk, 64);
            l_i[r] = l_i[r] * alpha + rs;
            m_i[r] = m_new;
#pragma unroll
            for (int nt = 0; nt < 4; nt++) o[nt][r] *= alpha;
            Ps[wave][(quad * 4 + r) * 40 + lane15] = f2bf(p0);
            Ps[wave][(quad * 4 + r) * 40 + 16 + lane15] = f2bf(p1);
        }
        // P (C-layout) -> A-layout via per-wave LDS round trip (in-order DS within wave)
        short8 pf = *(const short8*)&Ps[wave][lane15 * 40 + quad * 8];
#pragma unroll
        for (int nt = 0; nt < 4; nt++)
            o[nt] = __builtin_amdgcn_mfma_f32_16x16x32_bf16(pf, vf[nt], o[nt], 0, 0, 0);
    }

    ushort_t* yb = y + (size_t)b * T_SEQ * 768;
#pragma unroll
    for (int r = 0; r < 4; r++) {
        float rcp = 1.f / l_i[r];
        int q_r = qrow0 + quad * 4 + r;
#pragma unroll
        for (int nt = 0; nt < 4; nt++)
            yb[(size_t)q_r * 768 + h * 64 + nt * 16 + lane15] = f2bf(o[nt][r] * rcp);
    }
}

extern "C" void kernel_launch(void* const* d_in, const int* in_sizes, int n_in,
                              void* d_out, int out_size, void* d_ws, size_t ws_size,
                              hipStream_t stream) {
    (void)in_sizes; (void)n_in; (void)out_size; (void)ws_size;
    const float* x      = (const float*)d_in[0];
    const float* ln1_g  = (const float*)d_in[1];
    const float* ln1_b  = (const float*)d_in[2];
    const float* w_qkv  = (const float*)d_in[3];
    const float* w_o    = (const float*)d_in[4];
    const float* ln2_g  = (const float*)d_in[5];
    const float* ln2_b  = (const float*)d_in[6];
    const float* w_fc   = (const float*)d_in[7];
    const float* b_fc   = (const float*)d_in[8];
    const float* w_proj = (const float*)d_in[9];
    const float* b_proj = (const float*)d_in[10];

    char* ws = (char*)d_ws;
    // Layout (bytes):
    //   [0,          18874368)  qkv    bf16 4096x2304   } hff bf16 4096x3072 spans both later
    //   [18874368,   25165824)  ybuf   bf16 4096x768    }
    //   [25165824,   31457280)  xn     bf16 4096x768  / vt bf16 [2][12][64][2048] (after qkv GEMM, dead before LN2)
    //   [31457280,   34996224)  wqkvT  bf16 2304x768  } wprojT bf16 768x3072 spans both later
    //   [34996224,   36175872)  woT    bf16 768x768   }
    //   [36175872,   40894464)  wfcT   bf16 3072x768
    // Residual stream x2 lives in d_out (fp32), final GEMM reads+writes it in place.
    ushort_t* qkv    = (ushort_t*)(ws);
    ushort_t* ybuf   = (ushort_t*)(ws + 18874368);
    ushort_t* hff    = (ushort_t*)(ws);
    ushort_t* xn     = (ushort_t*)(ws + 25165824);
    ushort_t* vt     = (ushort_t*)(ws + 25165824);
    ushort_t* wqkvT  = (ushort_t*)(ws + 31457280);
    ushort_t* woT    = (ushort_t*)(ws + 34996224);
    ushort_t* wprojT = (ushort_t*)(ws + 31457280);
    ushort_t* wfcT   = (ushort_t*)(ws + 36175872);
    float* x2 = (float*)d_out;

    const int M = NB * T_SEQ;  // 4096

    wconv_kernel<<<dim3(12, 36), 256, 0, stream>>>(w_qkv, wqkvT, 768, 2304);
    wconv_kernel<<<dim3(12, 12), 256, 0, stream>>>(w_o, woT, 768, 768);
    wconv_kernel<<<dim3(12, 48), 256, 0, stream>>>(w_fc, wfcT, 768, 3072);
    ln_kernel<<<dim3(M), 256, 0, stream>>>(x, ln1_g, ln1_b, xn);
    gemm_bt_kernel<0, 0><<<dim3(32, 18), 256, 0, stream>>>(xn, wqkvT, nullptr, nullptr, qkv, M, 2304, 768);
    vtrans_kernel<<<dim3(32, 12, 2), 256, 0, stream>>>(qkv, vt);
    attn_kernel<<<dim3(32, 12, 2), 256, 0, stream>>>(qkv, vt, ybuf);
    gemm_bt_kernel<1, 1><<<dim3(32, 6), 256, 0, stream>>>(ybuf, woT, nullptr, x, x2, M, 768, 768);
    wconv_kernel<<<dim3(48, 12), 256, 0, stream>>>(w_proj, wprojT, 3072, 768);
    ln_kernel<<<dim3(M), 256, 0, stream>>>(x2, ln2_g, ln2_b, xn);
    gemm_bt_kernel<2, 0><<<dim3(32, 24), 256, 0, stream>>>(xn, wfcT, b_fc, nullptr, hff, M, 3072, 768);
    gemm_bt_kernel<3, 1><<<dim3(32, 6), 256, 0, stream>>>(hff, wprojT, b_proj, x2, x2, M, 768, 3072);
}